// Round 7
// baseline (1797.745 us; speedup 1.0000x reference)
//
#include <hip/hip_runtime.h>

// RGCN: hetero 2-layer GraphConv (mean aggr), MI355X.
// R7: bucket-push aggregation. R6's csr-gather was MLP-bound (accumulator-
// carried dependent loads, ~4 in flight) and needed binB+N-scans to build csr.
// New: binA bins packed (dl<<18|src) words by 128-dst bucket; push kernel =
// block per bucket, 128x65 fp32 LDS accumulator (LDS atomics, no load deps,
// unroll 4 -> 8 independent row loads in flight), mean+pack epilogue.
// Deletes binB, scan1/2/3, csr arrays. Dense MFMA GEMMs unchanged from R6.

#define FDIM 64
#define SH 7            // bucket = 128 dsts
#define PA_C 4096       // edges per binA block
typedef unsigned short u16;
typedef unsigned int u32;
typedef __bf16 bf16x8 __attribute__((ext_vector_type(8)));
typedef float f32x4 __attribute__((ext_vector_type(4)));

__device__ __forceinline__ u16 f2bf(float x) {  // RNE
  u32 b = __builtin_bit_cast(u32, x);
  b += 0x7FFFu + ((b >> 16) & 1u);
  return (u16)(b >> 16);
}
__device__ __forceinline__ float blo(u32 p) { return __builtin_bit_cast(float, p << 16); }
__device__ __forceinline__ float bhi(u32 p) { return __builtin_bit_cast(float, p & 0xffff0000u); }

// ---- weight conversion: 12 arrays fp32 -> bf16, optional +I (skip fold) ----
struct WTab {
  const float* src[12];
  u16* dst[12];
  int rows[12];
  int addI[12];
};
__global__ __launch_bounds__(256) void k_wconv(WTab p) {
  int b = blockIdx.x;
  const float* s = p.src[b];
  u16* d = p.dst[b];
  int n = p.rows[b] * 64;
  int addI = p.addI[b];
  for (int i = threadIdx.x; i < n; i += 256) {
    float v = s[i];
    if (addI && (i >> 6) == (i & 63)) v += 1.0f;
    d[i] = f2bf(v);
  }
}

// ---- fused degree count for both edge types ----
__global__ __launch_bounds__(256) void k_count2(const int* __restrict__ dstA, int E,
                                                int* __restrict__ cntA,
                                                const int* __restrict__ dstB,
                                                int* __restrict__ cntB) {
  int i = blockIdx.x * 256 + threadIdx.x;
  if (i < E) atomicAdd(&cntA[dstA[i]], 1);
  else if (i < 2 * E) atomicAdd(&cntB[dstB[i - E]], 1);
}

// ---- per-bucket edge count: block = bucket, sum 128 cnt values ----
struct BsumSide { const int* cnt; int* bcnt; int N; int nblk; };
__global__ __launch_bounds__(128) void k_dual_bsum(BsumSide A, BsumSide B) {
  int bid = blockIdx.x;
  const BsumSide& P = (bid < A.nblk) ? A : B;
  if (bid >= A.nblk) bid -= A.nblk;
  int t = threadIdx.x;
  int d = (bid << SH) + t;
  int v = (d < P.N) ? P.cnt[d] : 0;
#pragma unroll
  for (int m = 1; m < 64; m <<= 1) v += __shfl_xor(v, m, 64);
  __shared__ int sw[2];
  if ((t & 63) == 0) sw[t >> 6] = v;
  __syncthreads();
  if (t == 0) P.bcnt[bid] = sw[0] + sw[1];
}

// ---- bucket exclusive scan (nb <= 2048), one block per side ----
__global__ __launch_bounds__(1024) void k_bscan(const int* bcntA, int nbA, int* gbaseA, int* gcurA,
                                                const int* bcntB, int nbB, int* gbaseB, int* gcurB) {
  __shared__ int sd[1024];
  const int* bcnt; int nb; int* gbase; int* gcur;
  if (blockIdx.x == 0) { bcnt = bcntA; nb = nbA; gbase = gbaseA; gcur = gcurA; }
  else                 { bcnt = bcntB; nb = nbB; gbase = gbaseB; gcur = gcurB; }
  int t = threadIdx.x;
  int i0 = 2 * t, i1 = 2 * t + 1;
  int v0 = (i0 < nb) ? bcnt[i0] : 0;
  int v1 = (i1 < nb) ? bcnt[i1] : 0;
  int s = v0 + v1;
  sd[t] = s; __syncthreads();
  int sum = s;
  for (int off = 1; off < 1024; off <<= 1) {
    int x = (t >= off) ? sd[t - off] : 0;
    __syncthreads();
    sum += x; sd[t] = sum;
    __syncthreads();
  }
  int excl = sum - s;
  if (i0 < nb) { gbase[i0] = excl;      gcur[i0] = excl; }
  if (i1 < nb) { gbase[i1] = excl + v0; gcur[i1] = excl + v0; }
  if (t == 1023) gbase[nb] = sum;  // total
}

// ---- binA: bin edges into bucket-grouped packed words (dl<<18 | src) ----
struct BinSide { const int* src; const int* dst; int nb; int* gcur; u32* aux; int nblk; };
__global__ __launch_bounds__(256) void k_dual_binA(BinSide A, BinSide B, int E) {
  __shared__ int cnt[2048];
  __shared__ int base[2048];
  int bid = blockIdx.x;
  const BinSide& P = (bid < A.nblk) ? A : B;
  if (bid >= A.nblk) bid -= A.nblk;
  int t = threadIdx.x;
  int e0 = bid * PA_C;
  int n = min(PA_C, E - e0);
  int nb = P.nb;
  for (int b = t; b < nb; b += 256) cnt[b] = 0;
  __syncthreads();
  int ls[16], ld[16];
#pragma unroll
  for (int i = 0; i < 16; ++i) {
    int r = t + i * 256;
    if (r < n) {
      ls[i] = P.src[e0 + r];
      ld[i] = P.dst[e0 + r];
      atomicAdd(&cnt[ld[i] >> SH], 1);
    }
  }
  __syncthreads();
  for (int b = t; b < nb; b += 256) {
    int c = cnt[b];
    base[b] = c ? atomicAdd(&P.gcur[b], c) : 0;
  }
  __syncthreads();
  for (int b = t; b < nb; b += 256) cnt[b] = 0;
  __syncthreads();
#pragma unroll
  for (int i = 0; i < 16; ++i) {
    int r = t + i * 256;
    if (r < n) {
      int b = ld[i] >> SH;
      int p = base[b] + atomicAdd(&cnt[b], 1);
      P.aux[p] = ((u32)(ld[i] & ((1 << SH) - 1)) << 18) | (u32)ls[i];
    }
  }
}

// ---- bucket push-aggregate: block = bucket of 128 dsts, LDS fp32 acc ----
// lane = (half h -> edge parity, c -> u32 feature chunk). Per 2 edges:
// 2 aux loads (uniform/half) + 1 row load instr + 2 LDS atomics; loads are
// dependence-free across iterations -> unroll 4 keeps 8 rows in flight.
struct PushSide {
  const u32* xs; const u32* aux; const int* gbase; const int* cnt;
  u32* msg; int N; int nblk;
};
__global__ __launch_bounds__(256) void k_dual_push(PushSide A, PushSide B) {
  __shared__ float acc[128 * 65];
  int bid = blockIdx.x;
  const PushSide& P = (bid < A.nblk) ? A : B;
  if (bid >= A.nblk) bid -= A.nblk;
  int t = threadIdx.x;
  for (int i = t; i < 128 * 65; i += 256) acc[i] = 0.f;
  int d0 = bid << SH;
  int r0 = P.gbase[bid], r1 = P.gbase[bid + 1];
  __syncthreads();
  int lane = t & 63, w = t >> 6;
  int h = lane >> 5, c = lane & 31;
  const u32* aux = P.aux;
  const u32* xs = P.xs;
  int e = r0 + w * 2 + h;
  for (; e + 24 < r1; e += 32) {
    u32 p0 = aux[e];
    u32 p1 = aux[e + 8];
    u32 p2 = aux[e + 16];
    u32 p3 = aux[e + 24];
    u32 v0 = xs[(size_t)(p0 & 0x3FFFFu) * 32 + c];
    u32 v1 = xs[(size_t)(p1 & 0x3FFFFu) * 32 + c];
    u32 v2 = xs[(size_t)(p2 & 0x3FFFFu) * 32 + c];
    u32 v3 = xs[(size_t)(p3 & 0x3FFFFu) * 32 + c];
    atomicAdd(&acc[(p0 >> 18) * 65 + 2 * c],     blo(v0));
    atomicAdd(&acc[(p0 >> 18) * 65 + 2 * c + 1], bhi(v0));
    atomicAdd(&acc[(p1 >> 18) * 65 + 2 * c],     blo(v1));
    atomicAdd(&acc[(p1 >> 18) * 65 + 2 * c + 1], bhi(v1));
    atomicAdd(&acc[(p2 >> 18) * 65 + 2 * c],     blo(v2));
    atomicAdd(&acc[(p2 >> 18) * 65 + 2 * c + 1], bhi(v2));
    atomicAdd(&acc[(p3 >> 18) * 65 + 2 * c],     blo(v3));
    atomicAdd(&acc[(p3 >> 18) * 65 + 2 * c + 1], bhi(v3));
  }
  for (; e < r1; e += 8) {
    u32 p = aux[e];
    u32 v = xs[(size_t)(p & 0x3FFFFu) * 32 + c];
    atomicAdd(&acc[(p >> 18) * 65 + 2 * c],     blo(v));
    atomicAdd(&acc[(p >> 18) * 65 + 2 * c + 1], bhi(v));
  }
  __syncthreads();
  // epilogue: mean + bf16 pack, coalesced
  for (int i = t; i < 128 * 32; i += 256) {
    int dl = i >> 5, cc = i & 31;
    int d = d0 + dl;
    if (d < P.N) {
      float sc = 1.0f / fmaxf((float)P.cnt[d], 1.0f);
      u32 o = (u32)f2bf(acc[dl * 65 + 2 * cc] * sc) |
              ((u32)f2bf(acc[dl * 65 + 2 * cc + 1] * sc) << 16);
      P.msg[(size_t)d * 32 + cc] = o;
    }
  }
}

// ---- dual MFMA GEMM: Y[N,64](bf16) = act( A1 @ W1^T [+ A2 @ W2^T] + bias )
// Layouts (m89/m91/m120): A-frag A[m=lane&15][k=q*8+j]; B-frag = rows of W;
// C/D col=lane&15, row=q*4+reg.
struct GemmSide {
  const void* A1; const u16* A2; const u16* W1; const u16* W2;
  const float* bias; u16* Y; int N; int a1fp32; int dorelu; int nblk;
};
__device__ __forceinline__ void gemm64_body(const GemmSide& P, int bid) {
  const int t = threadIdx.x;
  const int w = t >> 6, lane = t & 63;
  const int c = lane & 15, q = lane >> 4;
  const int row0 = bid * 128 + w * 32;

  bf16x8 zf;
#pragma unroll
  for (int i = 0; i < 8; ++i) zf[i] = (__bf16)0.0f;

  f32x4 acc[2][4];
#pragma unroll
  for (int ms = 0; ms < 2; ++ms)
#pragma unroll
    for (int n = 0; n < 4; ++n) acc[ms][n] = f32x4{0.f, 0.f, 0.f, 0.f};

  const int nh = (P.A2 != nullptr) ? 2 : 1;
  for (int hh = 0; hh < nh; ++hh) {
    const u16* W = hh ? P.W2 : P.W1;
    bf16x8 bfr[4][2];
#pragma unroll
    for (int n = 0; n < 4; ++n)
#pragma unroll
      for (int kc = 0; kc < 2; ++kc)
        bfr[n][kc] = *(const bf16x8*)(W + (n * 16 + c) * 64 + kc * 32 + q * 8);
    bf16x8 afr[2][2];
#pragma unroll
    for (int ms = 0; ms < 2; ++ms) {
      int row = row0 + ms * 16 + c;
      bool ok = row < P.N;
#pragma unroll
      for (int kc = 0; kc < 2; ++kc) {
        if (hh == 0 && P.a1fp32) {
          bf16x8 v = zf;
          if (ok) {
            const float* Af = (const float*)P.A1 + (size_t)row * 64 + kc * 32 + q * 8;
            float4 u0 = *(const float4*)Af;
            float4 u1 = *(const float4*)(Af + 4);
            v[0] = (__bf16)u0.x; v[1] = (__bf16)u0.y; v[2] = (__bf16)u0.z; v[3] = (__bf16)u0.w;
            v[4] = (__bf16)u1.x; v[5] = (__bf16)u1.y; v[6] = (__bf16)u1.z; v[7] = (__bf16)u1.w;
          }
          afr[ms][kc] = v;
        } else {
          const u16* Ab = (hh == 0) ? (const u16*)P.A1 : P.A2;
          afr[ms][kc] = ok ? *(const bf16x8*)(Ab + (size_t)row * 64 + kc * 32 + q * 8) : zf;
        }
      }
    }
#pragma unroll
    for (int n = 0; n < 4; ++n)
#pragma unroll
      for (int ms = 0; ms < 2; ++ms)
#pragma unroll
        for (int kc = 0; kc < 2; ++kc)
          acc[ms][n] = __builtin_amdgcn_mfma_f32_16x16x32_bf16(afr[ms][kc], bfr[n][kc],
                                                               acc[ms][n], 0, 0, 0);
  }
#pragma unroll
  for (int n = 0; n < 4; ++n) {
    float bv = P.bias[n * 16 + c];
#pragma unroll
    for (int ms = 0; ms < 2; ++ms) {
#pragma unroll
      for (int r = 0; r < 4; ++r) {
        int row = row0 + ms * 16 + q * 4 + r;
        if (row < P.N) {
          float v = acc[ms][n][r] + bv;
          if (P.dorelu) v = fmaxf(v, 0.f);
          P.Y[(size_t)row * 64 + n * 16 + c] = f2bf(v);
        }
      }
    }
  }
}
__global__ __launch_bounds__(256) void k_dual_gemm(GemmSide A, GemmSide B) {
  if ((int)blockIdx.x < A.nblk) gemm64_body(A, blockIdx.x);
  else gemm64_body(B, blockIdx.x - A.nblk);
}

// ---- dual MFMA post linear: Y[N,32](fp32) = A(bf16) @ W[32,64]^T + bias ----
struct PostSide {
  const u16* A; const u16* W; const float* bias; float* Y; int N; int nblk;
};
__device__ __forceinline__ void postlin_body(const PostSide& P, int bid) {
  const int t = threadIdx.x;
  const int w = t >> 6, lane = t & 63;
  const int c = lane & 15, q = lane >> 4;
  const int row0 = bid * 128 + w * 32;

  bf16x8 zf;
#pragma unroll
  for (int i = 0; i < 8; ++i) zf[i] = (__bf16)0.0f;

  f32x4 acc[2][2];
#pragma unroll
  for (int ms = 0; ms < 2; ++ms)
#pragma unroll
    for (int n = 0; n < 2; ++n) acc[ms][n] = f32x4{0.f, 0.f, 0.f, 0.f};

  bf16x8 bfr[2][2];
#pragma unroll
  for (int n = 0; n < 2; ++n)
#pragma unroll
    for (int kc = 0; kc < 2; ++kc)
      bfr[n][kc] = *(const bf16x8*)(P.W + (n * 16 + c) * 64 + kc * 32 + q * 8);
  bf16x8 afr[2][2];
#pragma unroll
  for (int ms = 0; ms < 2; ++ms) {
    int row = row0 + ms * 16 + c;
    bool ok = row < P.N;
#pragma unroll
    for (int kc = 0; kc < 2; ++kc)
      afr[ms][kc] = ok ? *(const bf16x8*)(P.A + (size_t)row * 64 + kc * 32 + q * 8) : zf;
  }
#pragma unroll
  for (int n = 0; n < 2; ++n)
#pragma unroll
    for (int ms = 0; ms < 2; ++ms)
#pragma unroll
      for (int kc = 0; kc < 2; ++kc)
        acc[ms][n] = __builtin_amdgcn_mfma_f32_16x16x32_bf16(afr[ms][kc], bfr[n][kc],
                                                             acc[ms][n], 0, 0, 0);
#pragma unroll
  for (int n = 0; n < 2; ++n) {
    float bv = P.bias[n * 16 + c];
#pragma unroll
    for (int ms = 0; ms < 2; ++ms) {
#pragma unroll
      for (int r = 0; r < 4; ++r) {
        int row = row0 + ms * 16 + q * 4 + r;
        if (row < P.N) P.Y[(size_t)row * 32 + n * 16 + c] = acc[ms][n][r] + bv;
      }
    }
  }
}
__global__ __launch_bounds__(256) void k_dual_postlin(PostSide A, PostSide B) {
  if ((int)blockIdx.x < A.nblk) postlin_body(A, blockIdx.x);
  else postlin_body(B, blockIdx.x - A.nblk);
}

extern "C" void kernel_launch(void* const* d_in, const int* in_sizes, int n_in,
                              void* d_out, int out_size, void* d_ws, size_t ws_size,
                              hipStream_t stream) {
  const float* x_user = (const float*)d_in[0];
  const float* x_item = (const float*)d_in[1];
  const int* ei_u2i = (const int*)d_in[2];
  const int* ei_i2u = (const int*)d_in[3];

  const int NU = in_sizes[0] / FDIM;
  const int NI = in_sizes[1] / FDIM;
  const int E = in_sizes[2] / 2;

  const int nbI = (NI + (1 << SH) - 1) >> SH;   // 782
  const int nbU = (NU + (1 << SH) - 1) >> SH;   // 1563

  // ---- workspace ----
  u16* wsu = (u16*)d_ws;
  u16* h_u = wsu;   wsu += (size_t)NU * FDIM;
  u16* h_i = wsu;   wsu += (size_t)NI * FDIM;
  u16* x1_u = wsu;  wsu += (size_t)NU * FDIM;
  u16* x1_i = wsu;  wsu += (size_t)NI * FDIM;
  u16* msg_i = wsu; wsu += (size_t)NI * FDIM;
  u16* msg_u = wsu; wsu += (size_t)NU * FDIM;
  u16* wb = wsu;    wsu += 12 * 4096;
  int* wsi = (int*)wsu;
  int* cnt_i = wsi;   wsi += NI;    // contiguous with cnt_u: single memset
  int* cnt_u = wsi;   wsi += NU;
  int* bcnt_i = wsi;  wsi += nbI;
  int* bcnt_u = wsi;  wsi += nbU;
  int* gbase_i = wsi; wsi += nbI + 1;
  int* gbase_u = wsi; wsi += nbU + 1;
  int* gcur_i = wsi;  wsi += nbI;
  int* gcur_u = wsi;  wsi += nbU;
  u32* aux_i = (u32*)wsi; wsi += E;
  u32* aux_u = (u32*)wsi; wsi += E;

  const int* u2i_src = ei_u2i;
  const int* u2i_dst = ei_u2i + E;
  const int* i2u_src = ei_i2u;
  const int* i2u_dst = ei_i2u + E;

  const int gA = (E + PA_C - 1) / PA_C;  // 245 per side
  const int tU = (NU + 127) / 128;
  const int tI = (NI + 127) / 128;

  // ---- weight conversion (skip folded: wroot + I) ----
  WTab tab;
  const int widx[12] = {4, 6, 8, 10, 11, 13, 14, 16, 17, 19, 20, 22};
  const int addI[12] = {0, 0, 0, 1, 0, 1, 0, 1, 0, 1, 0, 0};
  const int rows_[12] = {64, 64, 64, 64, 64, 64, 64, 64, 64, 64, 32, 32};
  for (int i = 0; i < 12; ++i) {
    tab.src[i] = (const float*)d_in[widx[i]];
    tab.dst[i] = wb + i * 4096;
    tab.rows[i] = rows_[i];
    tab.addI[i] = addI[i];
  }
  k_wconv<<<12, 256, 0, stream>>>(tab);

  // ---- pre linears (dual): fp32 x -> bf16 h ----
  {
    GemmSide a{x_user, nullptr, wb + 0 * 4096, nullptr, (const float*)d_in[5],
               h_u, NU, 1, 0, tU};
    GemmSide b{x_item, nullptr, wb + 1 * 4096, nullptr, (const float*)d_in[7],
               h_i, NI, 1, 0, tI};
    k_dual_gemm<<<tU + tI, 256, 0, stream>>>(a, b);
  }

  // ---- graph prep: degrees, bucket counts, bucket scan, binning ----
  hipMemsetAsync(cnt_i, 0, (size_t)(NI + NU) * sizeof(int), stream);
  k_count2<<<(2 * E + 255) / 256, 256, 0, stream>>>(u2i_dst, E, cnt_i, i2u_dst, cnt_u);
  {
    BsumSide a{cnt_i, bcnt_i, NI, nbI};
    BsumSide b{cnt_u, bcnt_u, NU, nbU};
    k_dual_bsum<<<nbI + nbU, 128, 0, stream>>>(a, b);
  }
  k_bscan<<<2, 1024, 0, stream>>>(bcnt_i, nbI, gbase_i, gcur_i,
                                  bcnt_u, nbU, gbase_u, gcur_u);
  {
    BinSide a{u2i_src, u2i_dst, nbI, gcur_i, aux_i, gA};
    BinSide b{i2u_src, i2u_dst, nbU, gcur_u, aux_u, gA};
    k_dual_binA<<<2 * gA, 256, 0, stream>>>(a, b, E);
  }

  // ---- layer 1 ----
  {
    PushSide a{(const u32*)h_u, aux_i, gbase_i, cnt_i, (u32*)msg_i, NI, nbI};
    PushSide b{(const u32*)h_i, aux_u, gbase_u, cnt_u, (u32*)msg_u, NU, nbU};
    k_dual_push<<<nbI + nbU, 256, 0, stream>>>(a, b);
  }
  {
    GemmSide a{msg_i, h_i, wb + 2 * 4096, wb + 3 * 4096, (const float*)d_in[9],
               x1_i, NI, 0, 1, tI};
    GemmSide b{msg_u, h_u, wb + 4 * 4096, wb + 5 * 4096, (const float*)d_in[12],
               x1_u, NU, 0, 1, tU};
    k_dual_gemm<<<tI + tU, 256, 0, stream>>>(a, b);
  }

  // ---- layer 2 (outputs overwrite h_i / h_u) ----
  {
    PushSide a{(const u32*)x1_u, aux_i, gbase_i, cnt_i, (u32*)msg_i, NI, nbI};
    PushSide b{(const u32*)x1_i, aux_u, gbase_u, cnt_u, (u32*)msg_u, NU, nbU};
    k_dual_push<<<nbI + nbU, 256, 0, stream>>>(a, b);
  }
  {
    GemmSide a{msg_i, x1_i, wb + 6 * 4096, wb + 7 * 4096, (const float*)d_in[15],
               h_i, NI, 0, 1, tI};
    GemmSide b{msg_u, x1_u, wb + 8 * 4096, wb + 9 * 4096, (const float*)d_in[18],
               h_u, NU, 0, 1, tU};
    k_dual_gemm<<<tI + tU, 256, 0, stream>>>(a, b);
  }

  // ---- post linears (dual) -> fp32 d_out = [out_u | out_i] ----
  {
    float* out = (float*)d_out;
    PostSide a{h_u, wb + 10 * 4096, (const float*)d_in[21], out, NU, tU};
    PostSide b{h_i, wb + 11 * 4096, (const float*)d_in[23], out + (size_t)NU * 32, NI, tI};
    k_dual_postlin<<<tU + tI, 256, 0, stream>>>(a, b);
  }
}